// Round 3
// baseline (1579.502 us; speedup 1.0000x reference)
//
#include <hip/hip_runtime.h>
#include <hip/hip_bf16.h>

#define S2    0.70710678118654752f   // 1/sqrt(2)
#define S3    0.57735026918962576f   // 1/sqrt(3)
#define FAN   0.027950849718747373f  // 1/sqrt(128*10)
#define RSQ8  0.35355339059327378f   // 1/sqrt(8)
#define RSQ20 0.22360679774997896f   // 1/sqrt(20)

typedef __attribute__((ext_vector_type(8))) short bf16x8;
typedef __attribute__((ext_vector_type(4))) float f32x4;

__device__ __forceinline__ float silu_f(float v) {
    return v / (1.0f + __expf(-v));
}

// ---------------- sc (node skip-connection) kernel ----------------
__global__ __launch_bounds__(512) void sc_kernel(
    const float* __restrict__ na, const float* __restrict__ nf,
    const float* __restrict__ sw0, const float* __restrict__ sw1,
    float* __restrict__ out_sc)
{
    __shared__ float xls[512];
    __shared__ int vcls;
    const int n = blockIdx.x;
    const int t = threadIdx.x;
    xls[t] = nf[(size_t)n * 512 + t];
    if (t < 10 && na[n * 10 + t] > 0.5f) vcls = t;
    __syncthreads();
    const int v = vcls;
    float acc = 0.0f;
    if (t < 128) {
        const float* W = sw0 + v * 128 + t;   // (u*10+v)*128 + k
        #pragma unroll 8
        for (int u = 0; u < 128; ++u) acc += xls[u] * W[(size_t)u * 1280];
    } else {
        const int q = t - 128;
        const int c = q / 3;
        const int m = q - 3 * c;
        const float* W = sw1 + v * 128 + c;
        #pragma unroll 8
        for (int u = 0; u < 128; ++u) acc += xls[128 + u * 3 + m] * W[(size_t)u * 1280];
    }
    out_sc[(size_t)n * 512 + t] = acc * FAN;
}

// ---------------- W3 pre-convert: fp32 [128][512] -> bf16 B-fragments ----------------
__global__ __launch_bounds__(256) void conv_w3_kernel(
    const float* __restrict__ w13, const float* __restrict__ w23,
    ushort* __restrict__ bfrag)
{
    const int idx = blockIdx.x * 256 + threadIdx.x;  // 8192 total
    const int l  = idx & 63;
    const int ks = (idx >> 6) & 3;
    const int nt = idx >> 8;
    const int col = nt * 16 + (l & 15);
    const int k0  = ks * 32 + (l >> 4) * 8;
    #pragma unroll
    for (int j = 0; j < 8; ++j) {
        const int k = k0 + j;
        const float v = (k < 64) ? w13[(size_t)k * 512 + col]
                                 : w23[(size_t)(k - 64) * 512 + col];
        __hip_bfloat16 hb = __float2bfloat16(v * 0.125f);
        bfrag[(size_t)idx * 8 + j] = *reinterpret_cast<unsigned short*>(&hb);
    }
}

// ---------------- CSR build ----------------
__global__ void hist_kernel(const int* __restrict__ eidx, int* __restrict__ cnt, int E) {
    const int e = blockIdx.x * 256 + threadIdx.x;
    if (e < E) atomicAdd(&cnt[eidx[E + e]], 1);
}

__global__ __launch_bounds__(1024) void scan_kernel(
    const int* __restrict__ cnt, int* __restrict__ off,
    int* __restrict__ cursor, int n)
{
    __shared__ int part[1024];
    const int t = threadIdx.x;
    const int chunk = (n + 1023) / 1024;
    const int base = t * chunk;
    int s = 0;
    for (int i = 0; i < chunk; ++i) {
        const int idx = base + i;
        if (idx < n) s += cnt[idx];
    }
    part[t] = s;
    __syncthreads();
    for (int d = 1; d < 1024; d <<= 1) {
        const int v = (t >= d) ? part[t - d] : 0;
        __syncthreads();
        part[t] += v;
        __syncthreads();
    }
    int run = (t == 0) ? 0 : part[t - 1];
    for (int i = 0; i < chunk; ++i) {
        const int idx = base + i;
        if (idx < n) { off[idx] = run; cursor[idx] = run; run += cnt[idx]; }
    }
    if (t == 1023) off[n] = part[1023];
}

__global__ void scat_kernel(const int* __restrict__ eidx, int* __restrict__ cursor,
                            int* __restrict__ csr, int E) {
    const int e = blockIdx.x * 256 + threadIdx.x;
    if (e < E) {
        const int p = atomicAdd(&cursor[eidx[E + e]], 1);
        csr[p] = e;
    }
}

// ---------------- fused edge kernel ----------------
// MSG=1: write per-edge message rows to msgout. MSG=0: atomicAdd into bases.
template<int MSG>
__global__ __launch_bounds__(512) void edge_kernel(
    const float* __restrict__ nf, const float* __restrict__ ea,
    const float* __restrict__ ef, const float* __restrict__ xin,
    const float* __restrict__ w10, const float* __restrict__ w11,
    const float* __restrict__ w12,
    const float* __restrict__ w20, const float* __restrict__ w21,
    const float* __restrict__ w22,
    const ushort* __restrict__ bfrag,
    const int* __restrict__ eidx, float* __restrict__ outp, int E)
{
    __shared__ ushort hs[32 * 128];      // h3 concat, bf16, XOR-swizzled rows
    __shared__ float htA[8][64];
    __shared__ float htB[8][64];
    const int t = threadIdx.x;
    const int tile = blockIdx.x * 32;

    // ---- phase 1: early MLP layers (fp32 VALU), 8 waves x 4 iterations ----
    const int g = t >> 6, j = t & 63;
    for (int iter = 0; iter < 4; ++iter) {
        const int el = iter * 8 + g;
        const int e = tile + el;
        float acc = 0.f;
        #pragma unroll
        for (int i = 0; i < 8; ++i) acc += ef[(size_t)e * 8 + i] * w10[i * 64 + j];
        htA[g][j] = silu_f(acc * RSQ8);
        __syncthreads();
        acc = 0.f;
        #pragma unroll 8
        for (int i = 0; i < 64; ++i) acc += htA[g][i] * w11[i * 64 + j];
        htB[g][j] = silu_f(acc * 0.125f);
        __syncthreads();
        acc = 0.f;
        #pragma unroll 8
        for (int i = 0; i < 64; ++i) acc += htB[g][i] * w12[i * 64 + j];
        {
            __hip_bfloat16 hb = __float2bfloat16(silu_f(acc * 0.125f));
            *(ushort*)((char*)hs + el * 256 + ((j * 2) ^ ((el & 7) << 4))) =
                *reinterpret_cast<unsigned short*>(&hb);
        }
        // mlp2
        acc = 0.f;
        #pragma unroll
        for (int i = 0; i < 20; ++i) acc += xin[(size_t)e * 20 + i] * w20[i * 64 + j];
        htA[g][j] = silu_f(acc * RSQ20);
        __syncthreads();
        acc = 0.f;
        #pragma unroll 8
        for (int i = 0; i < 64; ++i) acc += htA[g][i] * w21[i * 64 + j];
        htB[g][j] = silu_f(acc * 0.125f);
        __syncthreads();
        acc = 0.f;
        #pragma unroll 8
        for (int i = 0; i < 64; ++i) acc += htB[g][i] * w22[i * 64 + j];
        {
            __hip_bfloat16 hb = __float2bfloat16(silu_f(acc * 0.125f));
            *(ushort*)((char*)hs + el * 256 + (((64 + j) * 2) ^ ((el & 7) << 4))) =
                *reinterpret_cast<unsigned short*>(&hb);
        }
        __syncthreads();
    }

    // ---- phase 2: w = h3 @ W3cat via bf16 MFMA ----
    const int wv = t >> 6;
    const int l  = t & 63;
    const int hi = l >> 4, lo = l & 15;

    f32x4 acc2[2][4];
    #pragma unroll
    for (int mt = 0; mt < 2; ++mt)
        #pragma unroll
        for (int q = 0; q < 4; ++q) acc2[mt][q] = (f32x4){0.f, 0.f, 0.f, 0.f};

    const char* hp = (const char*)hs;
    const bf16x8* bfv = (const bf16x8*)bfrag;
    #pragma unroll
    for (int ks = 0; ks < 4; ++ks) {
        bf16x8 afr[2];
        #pragma unroll
        for (int mt = 0; mt < 2; ++mt) {
            const int row = mt * 16 + lo;
            afr[mt] = *(const bf16x8*)(hp + row * 256 +
                        ((ks * 64 + hi * 16) ^ ((lo & 7) << 4)));
        }
        #pragma unroll
        for (int q = 0; q < 4; ++q) {
            const bf16x8 bfr = bfv[((q * 8 + wv) * 4 + ks) * 64 + l];
            #pragma unroll
            for (int mt = 0; mt < 2; ++mt)
                acc2[mt][q] = __builtin_amdgcn_mfma_f32_16x16x32_bf16(
                    afr[mt], bfr, acc2[mt][q], 0, 0, 0);
        }
    }

    // ---- phase 3: message epilogue ----
    const int c = wv * 16 + lo;
    #pragma unroll
    for (int mt = 0; mt < 2; ++mt) {
        #pragma unroll
        for (int r = 0; r < 4; ++r) {
            const int el = mt * 16 + hi * 4 + r;
            const int e = tile + el;
            const int s  = eidx[e];
            const float4 yv = *(const float4*)&ea[(size_t)e * 4];
            const float y0 = yv.x, y1a = yv.y, y1b = yv.z, y1c = yv.w;
            const float* nfr = nf + (size_t)s * 512;
            const float xs0 = nfr[c];
            const float x1a = nfr[128 + 3 * c], x1b = nfr[129 + 3 * c],
                        x1c = nfr[130 + 3 * c];
            const float wa = acc2[mt][0][r], wb = acc2[mt][1][r];
            const float wcv = acc2[mt][2][r], wd = acc2[mt][3][r];
            const float dot = x1a * y1a + x1b * y1b + x1c * y1c;
            const float m0  = S2 * 0.1f * (wa * xs0 * y0 + wd * dot * S3);
            const float m1a = S2 * 0.1f * (wb * xs0 * y1a + wcv * x1a * y0);
            const float m1b = S2 * 0.1f * (wb * xs0 * y1b + wcv * x1b * y0);
            const float m1c = S2 * 0.1f * (wb * xs0 * y1c + wcv * x1c * y0);
            if (MSG) {
                float* mr = outp + (size_t)e * 512;
                mr[c] = m0;
                mr[128 + 3 * c + 0] = m1a;
                mr[128 + 3 * c + 1] = m1b;
                mr[128 + 3 * c + 2] = m1c;
            } else {
                const int rr = eidx[E + e];
                float* br = outp + (size_t)rr * 512;
                atomicAdd(&br[c], m0);
                atomicAdd(&br[128 + 3 * c + 0], m1a);
                atomicAdd(&br[128 + 3 * c + 1], m1b);
                atomicAdd(&br[128 + 3 * c + 2], m1c);
            }
        }
    }
}

// ---------------- per-node gather (no atomics) ----------------
__global__ __launch_bounds__(512) void gather_kernel(
    const float* __restrict__ msg, const int* __restrict__ off,
    const int* __restrict__ csr, float* __restrict__ bases)
{
    const int n = blockIdx.x;
    const int t = threadIdx.x;
    const int s = off[n], e = off[n + 1];
    float acc = 0.f;
    int i = s;
    for (; i + 1 < e; i += 2) {
        const int e0 = csr[i], e1 = csr[i + 1];
        acc += msg[(size_t)e0 * 512 + t];
        acc += msg[(size_t)e1 * 512 + t];
    }
    if (i < e) acc += msg[(size_t)csr[i] * 512 + t];
    bases[(size_t)n * 512 + t] = acc;
}

extern "C" void kernel_launch(void* const* d_in, const int* in_sizes, int n_in,
                              void* d_out, int out_size, void* d_ws, size_t ws_size,
                              hipStream_t stream) {
    const float* na  = (const float*)d_in[0];
    const float* nf  = (const float*)d_in[1];
    const float* ea  = (const float*)d_in[2];
    const float* ef  = (const float*)d_in[3];
    const float* xin = (const float*)d_in[4];
    const int*   eidx= (const int*)d_in[5];
    const float* w10 = (const float*)d_in[7];
    const float* w20 = (const float*)d_in[8];
    const float* w11 = (const float*)d_in[9];
    const float* w21 = (const float*)d_in[10];
    const float* w12 = (const float*)d_in[11];
    const float* w22 = (const float*)d_in[12];
    const float* w13 = (const float*)d_in[13];
    const float* w23 = (const float*)d_in[14];
    const float* sw0 = (const float*)d_in[15];
    const float* sw1 = (const float*)d_in[16];

    const int N = in_sizes[1] / 512;
    const int E = in_sizes[2] / 4;

    float* bases  = (float*)d_out;
    float* out_sc = (float*)d_out + (size_t)N * 512;

    // ---- ws carve-up ----
    char* ws = (char*)d_ws;
    size_t o = 0;
    ushort* bfrag = (ushort*)(ws + o); o += 131072;
    int* cnt    = (int*)(ws + o); o += ((size_t)N * 4 + 255) & ~(size_t)255;
    int* off    = (int*)(ws + o); o += ((size_t)(N + 1) * 4 + 255) & ~(size_t)255;
    int* cursor = (int*)(ws + o); o += ((size_t)N * 4 + 255) & ~(size_t)255;
    int* csr    = (int*)(ws + o); o += ((size_t)E * 4 + 255) & ~(size_t)255;
    float* msg  = (float*)(ws + o);
    const size_t need = o + (size_t)E * 512 * 4;

    conv_w3_kernel<<<32, 256, 0, stream>>>(w13, w23, bfrag);
    sc_kernel<<<N, 512, 0, stream>>>(na, nf, sw0, sw1, out_sc);

    if (ws_size >= need) {
        // CSR build (ws is poisoned before timing -> zero cnt every launch)
        hipMemsetAsync(cnt, 0, (size_t)N * 4, stream);
        hist_kernel<<<(E + 255) / 256, 256, 0, stream>>>(eidx, cnt, E);
        scan_kernel<<<1, 1024, 0, stream>>>(cnt, off, cursor, N);
        scat_kernel<<<(E + 255) / 256, 256, 0, stream>>>(eidx, cursor, csr, E);

        edge_kernel<1><<<E / 32, 512, 0, stream>>>(nf, ea, ef, xin,
                                                   w10, w11, w12,
                                                   w20, w21, w22,
                                                   bfrag, eidx, msg, E);
        gather_kernel<<<N, 512, 0, stream>>>(msg, off, csr, bases);
    } else {
        // fallback: atomic scatter path
        hipMemsetAsync(bases, 0, (size_t)N * 512 * sizeof(float), stream);
        edge_kernel<0><<<E / 32, 512, 0, stream>>>(nf, ea, ef, xin,
                                                   w10, w11, w12,
                                                   w20, w21, w22,
                                                   bfrag, eidx, bases, E);
    }
}

// Round 5
// 1359.761 us; speedup vs baseline: 1.1616x; 1.1616x over previous
//
#include <hip/hip_runtime.h>
#include <hip/hip_bf16.h>

#define S2    0.70710678118654752f   // 1/sqrt(2)
#define S3    0.57735026918962576f   // 1/sqrt(3)
#define FAN   0.027950849718747373f  // 1/sqrt(128*10)
#define RSQ8  0.35355339059327378f   // 1/sqrt(8)
#define RSQ20 0.22360679774997896f   // 1/sqrt(20)

typedef __attribute__((ext_vector_type(8))) short bf16x8;
typedef __attribute__((ext_vector_type(4))) float f32x4;

__device__ __forceinline__ float silu_f(float v) {
    return v / (1.0f + __expf(-v));
}

// ---------------- sc (node skip-connection) kernel ----------------
__global__ __launch_bounds__(512) void sc_kernel(
    const float* __restrict__ na, const float* __restrict__ nf,
    const float* __restrict__ sw0, const float* __restrict__ sw1,
    float* __restrict__ out_sc)
{
    __shared__ float xls[512];
    __shared__ int vcls;
    const int n = blockIdx.x;
    const int t = threadIdx.x;
    xls[t] = nf[(size_t)n * 512 + t];
    if (t < 10 && na[n * 10 + t] > 0.5f) vcls = t;
    __syncthreads();
    const int v = vcls;
    float acc = 0.0f;
    if (t < 128) {
        const float* W = sw0 + v * 128 + t;   // (u*10+v)*128 + k
        #pragma unroll 8
        for (int u = 0; u < 128; ++u) acc += xls[u] * W[(size_t)u * 1280];
    } else {
        const int q = t - 128;
        const int c = q / 3;
        const int m = q - 3 * c;
        const float* W = sw1 + v * 128 + c;
        #pragma unroll 8
        for (int u = 0; u < 128; ++u) acc += xls[128 + u * 3 + m] * W[(size_t)u * 1280];
    }
    out_sc[(size_t)n * 512 + t] = acc * FAN;
}

// ---------------- W3 pre-convert: fp32 [128][512] -> bf16 B-fragments ----------------
__global__ __launch_bounds__(256) void conv_w3_kernel(
    const float* __restrict__ w13, const float* __restrict__ w23,
    ushort* __restrict__ bfrag)
{
    const int idx = blockIdx.x * 256 + threadIdx.x;  // 8192 total
    const int l  = idx & 63;
    const int ks = (idx >> 6) & 3;
    const int nt = idx >> 8;
    const int col = nt * 16 + (l & 15);
    const int k0  = ks * 32 + (l >> 4) * 8;
    #pragma unroll
    for (int j = 0; j < 8; ++j) {
        const int k = k0 + j;
        const float v = (k < 64) ? w13[(size_t)k * 512 + col]
                                 : w23[(size_t)(k - 64) * 512 + col];
        __hip_bfloat16 hb = __float2bfloat16(v * 0.125f);
        bfrag[(size_t)idx * 8 + j] = *reinterpret_cast<unsigned short*>(&hb);
    }
}

// ---------------- CSR build (padded to multiples of 4 per node) ----------------
__global__ void hist_kernel(const int* __restrict__ eidx, int* __restrict__ cnt, int E) {
    const int e = blockIdx.x * 256 + threadIdx.x;
    if (e < E) atomicAdd(&cnt[eidx[E + e]], 1);
}

__global__ __launch_bounds__(1024) void scan_kernel(
    const int* __restrict__ cnt, int* __restrict__ off,
    int* __restrict__ cursor, int n)
{
    __shared__ int part[1024];
    const int t = threadIdx.x;
    const int chunk = (n + 1023) / 1024;
    const int base = t * chunk;
    int s = 0;
    for (int i = 0; i < chunk; ++i) {
        const int idx = base + i;
        if (idx < n) s += (cnt[idx] + 3) & ~3;   // padded size
    }
    part[t] = s;
    __syncthreads();
    for (int d = 1; d < 1024; d <<= 1) {
        const int v = (t >= d) ? part[t - d] : 0;
        __syncthreads();
        part[t] += v;
        __syncthreads();
    }
    int run = (t == 0) ? 0 : part[t - 1];
    for (int i = 0; i < chunk; ++i) {
        const int idx = base + i;
        if (idx < n) {
            off[idx] = run; cursor[idx] = run;
            run += (cnt[idx] + 3) & ~3;
        }
    }
    if (t == 1023) off[n] = part[1023];          // padded total
}

__global__ void scat_kernel(const int* __restrict__ eidx, int* __restrict__ cursor,
                            int* __restrict__ csr, int E) {
    const int e = blockIdx.x * 256 + threadIdx.x;
    if (e < E) {
        const int p = atomicAdd(&cursor[eidx[E + e]], 1);
        csr[p] = e;
    }
}

// ---------------- fused edge kernel ----------------
// SORTED=1: tiles walk the padded receiver-sorted csr; messages merged in LDS
//           bins, flushed as ~3 coalesced row-atomics per tile.
// SORTED=0: fallback — per-edge atomic scatter (R2 behavior).
template<int SORTED>
__global__ __launch_bounds__(512) void edge_kernel(
    const float* __restrict__ nf, const float* __restrict__ ea,
    const float* __restrict__ ef, const float* __restrict__ xin,
    const float* __restrict__ w10, const float* __restrict__ w11,
    const float* __restrict__ w12,
    const float* __restrict__ w20, const float* __restrict__ w21,
    const float* __restrict__ w22,
    const ushort* __restrict__ bfrag,
    const int* __restrict__ eidx, const int* __restrict__ csr,
    const int* __restrict__ totp,
    float* __restrict__ bases, int E)
{
    __shared__ ushort hs[32 * 128];      // h3 concat, bf16, XOR-swizzled rows
    __shared__ float htA[8][64];
    __shared__ float htB[8][64];
    const int t = threadIdx.x;
    const int tile0 = blockIdx.x * 32;

    if (SORTED) {
        if (tile0 >= totp[0]) return;    // block-uniform early exit
    }

    // ---- phase 1: early MLP layers (R2's proven barrier pattern) ----
    const int g = t >> 6, j = t & 63;
    for (int iter = 0; iter < 4; ++iter) {
        const int el = iter * 8 + g;
        const int slot = tile0 + el;
        const int eid = SORTED ? csr[slot] : slot;
        float acc = 0.f;
        if (!SORTED || eid >= 0) {
            #pragma unroll
            for (int i = 0; i < 8; ++i) acc += ef[(size_t)eid * 8 + i] * w10[i * 64 + j];
        }
        htA[g][j] = silu_f(acc * RSQ8);
        __syncthreads();
        acc = 0.f;
        #pragma unroll 8
        for (int i = 0; i < 64; ++i) acc += htA[g][i] * w11[i * 64 + j];
        htB[g][j] = silu_f(acc * 0.125f);
        __syncthreads();
        acc = 0.f;
        #pragma unroll 8
        for (int i = 0; i < 64; ++i) acc += htB[g][i] * w12[i * 64 + j];
        {
            __hip_bfloat16 hb = __float2bfloat16(silu_f(acc * 0.125f));
            *(ushort*)((char*)hs + el * 256 + ((j * 2) ^ ((el & 7) << 4))) =
                *reinterpret_cast<unsigned short*>(&hb);
        }
        // mlp2
        acc = 0.f;
        if (!SORTED || eid >= 0) {
            #pragma unroll
            for (int i = 0; i < 20; ++i) acc += xin[(size_t)eid * 20 + i] * w20[i * 64 + j];
        }
        htA[g][j] = silu_f(acc * RSQ20);
        __syncthreads();
        acc = 0.f;
        #pragma unroll 8
        for (int i = 0; i < 64; ++i) acc += htA[g][i] * w21[i * 64 + j];
        htB[g][j] = silu_f(acc * 0.125f);
        __syncthreads();
        acc = 0.f;
        #pragma unroll 8
        for (int i = 0; i < 64; ++i) acc += htB[g][i] * w22[i * 64 + j];
        {
            __hip_bfloat16 hb = __float2bfloat16(silu_f(acc * 0.125f));
            *(ushort*)((char*)hs + el * 256 + (((64 + j) * 2) ^ ((el & 7) << 4))) =
                *reinterpret_cast<unsigned short*>(&hb);
        }
        __syncthreads();
    }

    // ---- phase 2: w = h3 @ W3cat via bf16 MFMA ----
    const int wv = t >> 6;
    const int l  = t & 63;
    const int hi = l >> 4, lo = l & 15;

    f32x4 acc2[2][4];
    #pragma unroll
    for (int mt = 0; mt < 2; ++mt)
        #pragma unroll
        for (int q = 0; q < 4; ++q) acc2[mt][q] = (f32x4){0.f, 0.f, 0.f, 0.f};

    const char* hp = (const char*)hs;
    const bf16x8* bfv = (const bf16x8*)bfrag;
    #pragma unroll
    for (int ks = 0; ks < 4; ++ks) {
        bf16x8 afr[2];
        #pragma unroll
        for (int mt = 0; mt < 2; ++mt) {
            const int row = mt * 16 + lo;
            afr[mt] = *(const bf16x8*)(hp + row * 256 +
                        ((ks * 64 + hi * 16) ^ ((lo & 7) << 4)));
        }
        #pragma unroll
        for (int q = 0; q < 4; ++q) {
            const bf16x8 bfr = bfv[((q * 8 + wv) * 4 + ks) * 64 + l];
            #pragma unroll
            for (int mt = 0; mt < 2; ++mt)
                acc2[mt][q] = __builtin_amdgcn_mfma_f32_16x16x32_bf16(
                    afr[mt], bfr, acc2[mt][q], 0, 0, 0);
        }
    }

    // ---- phase 3: message epilogue ----
    const int c = wv * 16 + lo;
    if (SORTED) {
        // CRITICAL: all waves must finish reading hs (phase 2) before any
        // phase-3 shared-memory writes (run_rec/bins may alias hs in LDS).
        __syncthreads();
        __shared__ float bins[8][512];
        __shared__ int run_rec[8], run_bin[8], bin_rec[8];
        __shared__ int nbins_s;
        if (t < 8) {
            const int e0 = csr[tile0 + t * 4];   // run start is a real edge
            run_rec[t] = (e0 >= 0) ? eidx[E + e0] : -1;
        }
        __syncthreads();
        if (t == 0) {
            int nb = 0;
            for (int i = 0; i < 8; ++i) {
                const int r = run_rec[i];
                if (r < 0) { run_bin[i] = -1; continue; }
                int b = -1;
                for (int jj = 0; jj < i; ++jj)
                    if (run_rec[jj] == r) { b = run_bin[jj]; break; }
                if (b < 0) { b = nb; bin_rec[nb] = r; ++nb; }
                run_bin[i] = b;
            }
            nbins_s = nb;
        }
        #pragma unroll
        for (int b = 0; b < 8; ++b) bins[b][t] = 0.f;
        __syncthreads();

        #pragma unroll
        for (int mt = 0; mt < 2; ++mt) {
            const int b = run_bin[mt * 4 + hi];
            if (b < 0) continue;
            float am0 = 0.f, am1a = 0.f, am1b = 0.f, am1c = 0.f;
            #pragma unroll
            for (int r = 0; r < 4; ++r) {
                const int el = mt * 16 + hi * 4 + r;
                const int e = csr[tile0 + el];
                if (e < 0) continue;
                const int s = eidx[e];
                const float4 yv = *(const float4*)&ea[(size_t)e * 4];
                const float y0 = yv.x, y1a = yv.y, y1b = yv.z, y1c = yv.w;
                const float* nfr = nf + (size_t)s * 512;
                const float xs0 = nfr[c];
                const float x1a = nfr[128 + 3 * c], x1b = nfr[129 + 3 * c],
                            x1c = nfr[130 + 3 * c];
                const float wa = acc2[mt][0][r], wb = acc2[mt][1][r];
                const float wcv = acc2[mt][2][r], wd = acc2[mt][3][r];
                const float dot = x1a * y1a + x1b * y1b + x1c * y1c;
                am0  += S2 * 0.1f * (wa * xs0 * y0 + wd * dot * S3);
                am1a += S2 * 0.1f * (wb * xs0 * y1a + wcv * x1a * y0);
                am1b += S2 * 0.1f * (wb * xs0 * y1b + wcv * x1b * y0);
                am1c += S2 * 0.1f * (wb * xs0 * y1c + wcv * x1c * y0);
            }
            atomicAdd(&bins[b][c], am0);
            atomicAdd(&bins[b][128 + 3 * c + 0], am1a);
            atomicAdd(&bins[b][128 + 3 * c + 1], am1b);
            atomicAdd(&bins[b][128 + 3 * c + 2], am1c);
        }
        __syncthreads();
        const int nb = nbins_s;
        for (int b = 0; b < nb; ++b)
            atomicAdd(&bases[(size_t)bin_rec[b] * 512 + t], bins[b][t]);
    } else {
        #pragma unroll
        for (int mt = 0; mt < 2; ++mt) {
            #pragma unroll
            for (int r = 0; r < 4; ++r) {
                const int el = mt * 16 + hi * 4 + r;
                const int e = tile0 + el;
                const int s  = eidx[e];
                const float4 yv = *(const float4*)&ea[(size_t)e * 4];
                const float y0 = yv.x, y1a = yv.y, y1b = yv.z, y1c = yv.w;
                const float* nfr = nf + (size_t)s * 512;
                const float xs0 = nfr[c];
                const float x1a = nfr[128 + 3 * c], x1b = nfr[129 + 3 * c],
                            x1c = nfr[130 + 3 * c];
                const float wa = acc2[mt][0][r], wb = acc2[mt][1][r];
                const float wcv = acc2[mt][2][r], wd = acc2[mt][3][r];
                const float dot = x1a * y1a + x1b * y1b + x1c * y1c;
                const int rr = eidx[E + e];
                float* br = bases + (size_t)rr * 512;
                atomicAdd(&br[c],               S2 * 0.1f * (wa * xs0 * y0 + wd * dot * S3));
                atomicAdd(&br[128 + 3 * c + 0], S2 * 0.1f * (wb * xs0 * y1a + wcv * x1a * y0));
                atomicAdd(&br[128 + 3 * c + 1], S2 * 0.1f * (wb * xs0 * y1b + wcv * x1b * y0));
                atomicAdd(&br[128 + 3 * c + 2], S2 * 0.1f * (wb * xs0 * y1c + wcv * x1c * y0));
            }
        }
    }
}

extern "C" void kernel_launch(void* const* d_in, const int* in_sizes, int n_in,
                              void* d_out, int out_size, void* d_ws, size_t ws_size,
                              hipStream_t stream) {
    const float* na  = (const float*)d_in[0];
    const float* nf  = (const float*)d_in[1];
    const float* ea  = (const float*)d_in[2];
    const float* ef  = (const float*)d_in[3];
    const float* xin = (const float*)d_in[4];
    const int*   eidx= (const int*)d_in[5];
    const float* w10 = (const float*)d_in[7];
    const float* w20 = (const float*)d_in[8];
    const float* w11 = (const float*)d_in[9];
    const float* w21 = (const float*)d_in[10];
    const float* w12 = (const float*)d_in[11];
    const float* w22 = (const float*)d_in[12];
    const float* w13 = (const float*)d_in[13];
    const float* w23 = (const float*)d_in[14];
    const float* sw0 = (const float*)d_in[15];
    const float* sw1 = (const float*)d_in[16];

    const int N = in_sizes[1] / 512;
    const int E = in_sizes[2] / 4;

    float* bases  = (float*)d_out;
    float* out_sc = (float*)d_out + (size_t)N * 512;

    // padded csr upper bound, rounded to whole 32-edge tiles
    const size_t capE = ((size_t)E + 3 * (size_t)N + 31) & ~(size_t)31;
    const int nblk = (int)(capE / 32);

    // ---- ws carve-up (≈2 MB total) ----
    char* ws = (char*)d_ws;
    size_t o = 0;
    ushort* bfrag = (ushort*)(ws + o); o += 131072;
    int* cnt    = (int*)(ws + o); o += ((size_t)N * 4 + 255) & ~(size_t)255;
    int* off    = (int*)(ws + o); o += ((size_t)(N + 1) * 4 + 255) & ~(size_t)255;
    int* cursor = (int*)(ws + o); o += ((size_t)N * 4 + 255) & ~(size_t)255;
    int* csr    = (int*)(ws + o); o += capE * 4;
    const size_t need = o;

    conv_w3_kernel<<<32, 256, 0, stream>>>(w13, w23, bfrag);
    sc_kernel<<<N, 512, 0, stream>>>(na, nf, sw0, sw1, out_sc);
    hipMemsetAsync(bases, 0, (size_t)N * 512 * sizeof(float), stream);

    if (ws_size >= need) {
        hipMemsetAsync(cnt, 0, (size_t)N * 4, stream);
        hipMemsetAsync(csr, 0xFF, capE * 4, stream);   // -1 sentinels
        hist_kernel<<<(E + 255) / 256, 256, 0, stream>>>(eidx, cnt, E);
        scan_kernel<<<1, 1024, 0, stream>>>(cnt, off, cursor, N);
        scat_kernel<<<(E + 255) / 256, 256, 0, stream>>>(eidx, cursor, csr, E);

        edge_kernel<1><<<nblk, 512, 0, stream>>>(nf, ea, ef, xin,
                                                 w10, w11, w12,
                                                 w20, w21, w22,
                                                 bfrag, eidx, csr, off + N,
                                                 bases, E);
    } else {
        edge_kernel<0><<<E / 32, 512, 0, stream>>>(nf, ea, ef, xin,
                                                   w10, w11, w12,
                                                   w20, w21, w22,
                                                   bfrag, eidx, (const int*)nullptr,
                                                   (const int*)nullptr, bases, E);
    }
}